// Round 4
// baseline (3125.789 us; speedup 1.0000x reference)
//
#include <hip/hip_runtime.h>

#define BB   64
#define SS   1024
#define HH   256
#define OUTD 768
#define TT   16
#define DOUT 512
#define DIN  512
#define NBLK 256

typedef __attribute__((ext_vector_type(8))) short short8;
typedef __attribute__((ext_vector_type(4))) short short4v;
typedef __attribute__((ext_vector_type(4))) float f32x4;

__device__ __forceinline__ unsigned short f2bf(float f) {
    unsigned u = __builtin_bit_cast(unsigned, f);
    u += 0x7FFFu + ((u >> 16) & 1u);
    return (unsigned short)(u >> 16);
}
__device__ __forceinline__ float bf2f(unsigned short h) {
    unsigned u = ((unsigned)h) << 16;
    return __builtin_bit_cast(float, u);
}

// ---------------------------------------------------------------------------
// Hand-rolled grid barrier (two-counter + generation). Requires co-residency
// (cooperative launch). bar[0]=arrive count, bar[1]=generation.
// ---------------------------------------------------------------------------
__device__ __forceinline__ void grid_barrier(unsigned* bar)
{
    __syncthreads();
    if (threadIdx.x == 0) {
        __threadfence();   // release: drain this block's stores to device scope
        unsigned g0 = __hip_atomic_load(&bar[1], __ATOMIC_RELAXED,
                                        __HIP_MEMORY_SCOPE_AGENT);
        unsigned old = __hip_atomic_fetch_add(&bar[0], 1u, __ATOMIC_ACQ_REL,
                                              __HIP_MEMORY_SCOPE_AGENT);
        if (old == NBLK - 1) {
            __hip_atomic_store(&bar[0], 0u, __ATOMIC_RELAXED,
                               __HIP_MEMORY_SCOPE_AGENT);
            __hip_atomic_store(&bar[1], g0 + 1u, __ATOMIC_RELEASE,
                               __HIP_MEMORY_SCOPE_AGENT);
        } else {
            while (__hip_atomic_load(&bar[1], __ATOMIC_ACQUIRE,
                                     __HIP_MEMORY_SCOPE_AGENT) == g0)
                __builtin_amdgcn_s_sleep(1);
        }
    }
    __syncthreads();
}

// ---------------------------------------------------------------------------
struct LayerArgs {
    const float* W;                 // [4096][Kin]
    const float* bias;              // [4096]
    const unsigned short* uHi;      // [T][64][Ku]
    const unsigned short* uLo;
    unsigned short* hHi;            // [T][64][256]  (this layer)
    unsigned short* hLo;
    float* cB;                      // [T][64][1024] (this layer)
    unsigned short* outHi;          // [T][64][768]  next-layer input / final
    unsigned short* outLo;
    float* o1F;                     // layer1: write; layer3: read (residual)
    unsigned* bar;
    int Ku, Kin, dil, isL1, isL3;
};

// One kernel per layer; loops t=0..15 internally with one grid barrier per t.
// Block b owns state columns j0=b*4..+3 (all 4 gates => 16 W rows, in LDS).
// 8 waves, 8-way K-split, LDS reduce, block-local LSTM epilogue.
__global__ __launch_bounds__(512, 1) void layer_kernel(LayerArgs a)
{
    __shared__ short wfrag[40960];      // hi: [0,20480) lo: [20480,40960)
    __shared__ float red[32 * 272];     // [wave*4+m][(r4+i)*17+c]
    __shared__ float Dsum[64 * 17];

    const int tid  = threadIdx.x;
    const int lane = tid & 63;
    const int w    = tid >> 6;
    const int j0   = blockIdx.x * 4;
    const int l15  = lane & 15;
    const int lk8  = (lane >> 4) * 8;
    const int Kin  = a.Kin, Ku = a.Ku;

    // ---- prologue: load 16 W rows (fp32), split hi/lo, store in frag order
    const int kq4 = Kin >> 2;
    for (int i = tid; i < 4 * Kin; i += 512) {
        int row = i / kq4;
        int k   = (i - row * kq4) * 4;
        int g   = row >> 2, jj = row & 3;
        f32x4 wv = *reinterpret_cast<const f32x4*>(
            a.W + (size_t)(g * SS + j0 + jj) * Kin + k);
        short4v sh, sl;
        #pragma unroll
        for (int q = 0; q < 4; ++q) {
            unsigned short hb = f2bf(wv[q]);
            sh[q] = (short)hb; sl[q] = (short)f2bf(wv[q] - bf2f(hb));
        }
        int s = k >> 5, sub = k & 31;
        int ln = (sub >> 3) * 16 + row;
        int off = ((s * 64 + ln) << 3) + (sub & 7);
        *reinterpret_cast<short4v*>(&wfrag[off])         = sh;
        *reinterpret_cast<short4v*>(&wfrag[20480 + off]) = sl;
    }
    __syncthreads();

    for (int t = 0; t < TT; ++t) {
        const int prev_ok    = (t > 0);
        const int delayed_ok = (t >= a.dil);
        const int tm1 = prev_ok ? t - 1 : 0;
        const int td  = delayed_ok ? t - a.dil : tm1;

        const unsigned short* uHi = a.uHi + (size_t)t * BB * Ku;
        const unsigned short* uLo = a.uLo + (size_t)t * BB * Ku;
        const unsigned short* hPrevHi = a.hHi + (size_t)tm1 * BB * HH;
        const unsigned short* hPrevLo = a.hLo + (size_t)tm1 * BB * HH;
        const unsigned short* hDelHi  = a.hHi + (size_t)td  * BB * HH;
        const unsigned short* hDelLo  = a.hLo + (size_t)td  * BB * HH;

        const int Keff   = prev_ok ? Kin : Ku;
        const int Kslice = Keff >> 3;
        const int nsteps = Kslice >> 5;

        f32x4 acc[4] = {{0,0,0,0},{0,0,0,0},{0,0,0,0},{0,0,0,0}};
        int kb = w * Kslice;
        for (int s = 0; s < nsteps; ++s, kb += 32) {
            short8 whi = *reinterpret_cast<const short8*>(
                &wfrag[((kb >> 5) * 64 + lane) << 3]);
            short8 wlo = *reinterpret_cast<const short8*>(
                &wfrag[20480 + (((kb >> 5) * 64 + lane) << 3)]);
            const unsigned short *pHi, *pLo; int stride, koff;
            if (kb < Ku)            { pHi = uHi;     pLo = uLo;     stride = Ku; koff = kb; }
            else if (kb < Ku + HH)  { pHi = hPrevHi; pLo = hPrevLo; stride = HH; koff = kb - Ku; }
            else                    { pHi = hDelHi;  pLo = hDelLo;  stride = HH; koff = kb - Ku - HH; }
            const int ao = koff + lk8;
            #pragma unroll
            for (int m = 0; m < 4; ++m) {
                const int r = m * 16 + l15;
                short8 ahi = *reinterpret_cast<const short8*>(pHi + (size_t)r * stride + ao);
                short8 alo = *reinterpret_cast<const short8*>(pLo + (size_t)r * stride + ao);
                acc[m] = __builtin_amdgcn_mfma_f32_16x16x32_bf16(ahi, whi, acc[m], 0, 0, 0);
                acc[m] = __builtin_amdgcn_mfma_f32_16x16x32_bf16(alo, whi, acc[m], 0, 0, 0);
                acc[m] = __builtin_amdgcn_mfma_f32_16x16x32_bf16(ahi, wlo, acc[m], 0, 0, 0);
            }
        }

        // partials -> LDS (C/D layout: col = lane&15, row = (lane>>4)*4 + i)
        {
            const int c  = lane & 15;
            const int r4 = (lane >> 4) * 4;
            #pragma unroll
            for (int m = 0; m < 4; ++m)
                #pragma unroll
                for (int i = 0; i < 4; ++i)
                    red[(w * 4 + m) * 272 + (r4 + i) * 17 + c] = acc[m][i];
        }
        __syncthreads();

        // cross-wave reduce: 1024 outputs, 2 per thread
        #pragma unroll
        for (int e2 = 0; e2 < 2; ++e2) {
            const int e  = tid + e2 * 512;
            const int m  = e >> 8;
            const int rr = (e >> 4) & 15;
            const int c  = e & 15;
            float sum = 0.f;
            #pragma unroll
            for (int w2 = 0; w2 < 8; ++w2)
                sum += red[(w2 * 4 + m) * 272 + rr * 17 + c];
            Dsum[(m * 16 + rr) * 17 + c] = sum;
        }
        __syncthreads();

        // block-local LSTM epilogue: 64 rows x 4 cols (threads 0..255)
        if (tid < 256) {
            const int r  = tid >> 2;
            const int jj = tid & 3;
            const int j  = j0 + jj;
            float g0 = Dsum[r * 17 + 0  + jj] + a.bias[j];
            float g1 = Dsum[r * 17 + 4  + jj] + a.bias[SS + j];
            float g2 = Dsum[r * 17 + 8  + jj] + a.bias[2 * SS + j];
            float g3 = Dsum[r * 17 + 12 + jj] + a.bias[3 * SS + j];

            float f = 1.f / (1.f + __expf(-(g0 + 1.f)));
            float n = tanhf(g1);
            float av = 1.f / (1.f + __expf(-g2));
            float o = 1.f / (1.f + __expf(-g3));

            float pC = prev_ok ? a.cB[(size_t)tm1 * BB * SS + r * SS + j] : 0.f;
            float dC = delayed_ok ? a.cB[(size_t)td * BB * SS + r * SS + j] : pC;
            float wC = delayed_ok ? (av * pC + (1.f - av) * dC) : pC;
            float nf = prev_ok ? (f * wC + (1.f - f) * n) : n;
            float wh = o * nf;

            a.cB[(size_t)t * BB * SS + r * SS + j] = nf;

            if (j < OUTD) {
                float v = wh;
                const size_t oidx = (size_t)t * BB * OUTD + r * OUTD + j;
                if (a.isL3) v += a.o1F[oidx];
                if (a.isL1) a.o1F[oidx] = v;
                unsigned short hb = f2bf(v);
                a.outHi[oidx] = hb;
                a.outLo[oidx] = f2bf(v - bf2f(hb));
            } else {
                const int jo = j - OUTD;
                const size_t hidx = (size_t)t * BB * HH + r * HH + jo;
                unsigned short hb = f2bf(wh);
                a.hHi[hidx] = hb;
                a.hLo[hidx] = f2bf(wh - bf2f(hb));
            }
        }
        if (t < TT - 1) grid_barrier(a.bar);
    }
}

// ---------------------------------------------------------------------------
// Adaptor: Y[1024][512] = A[1024][768] @ Wa[512][768]^T + ba, 3-pass MFMA.
// ---------------------------------------------------------------------------
__global__ __launch_bounds__(512) void adaptor_mfma(
    const unsigned short* __restrict__ Ahi, const unsigned short* __restrict__ Alo,
    const float* __restrict__ Wa, const float* __restrict__ ba,
    float* __restrict__ Y)
{
    const int tid  = threadIdx.x;
    const int lane = tid & 63;
    const int w    = tid >> 6;
    const int n0   = blockIdx.x * 16;
    const int r0   = blockIdx.y * 256 + w * 32;
    const int l15  = lane & 15;
    const int lk8  = (lane >> 4) * 8;

    f32x4 acc[2] = {{0,0,0,0},{0,0,0,0}};
    const float* Wrow = Wa + (size_t)(n0 + l15) * OUTD + lk8;
    for (int kb = 0; kb < OUTD; kb += 32) {
        f32x4 wv0 = *reinterpret_cast<const f32x4*>(Wrow + kb);
        f32x4 wv1 = *reinterpret_cast<const f32x4*>(Wrow + kb + 4);
        short8 whi, wlo;
        #pragma unroll
        for (int j = 0; j < 4; ++j) {
            unsigned short hb = f2bf(wv0[j]);
            whi[j] = (short)hb; wlo[j] = (short)f2bf(wv0[j] - bf2f(hb));
            unsigned short hb2 = f2bf(wv1[j]);
            whi[4+j] = (short)hb2; wlo[4+j] = (short)f2bf(wv1[j] - bf2f(hb2));
        }
        #pragma unroll
        for (int m = 0; m < 2; ++m) {
            const int r = r0 + m * 16 + l15;
            short8 ahi = *reinterpret_cast<const short8*>(Ahi + (size_t)r * OUTD + kb + lk8);
            short8 alo = *reinterpret_cast<const short8*>(Alo + (size_t)r * OUTD + kb + lk8);
            acc[m] = __builtin_amdgcn_mfma_f32_16x16x32_bf16(ahi, whi, acc[m], 0, 0, 0);
            acc[m] = __builtin_amdgcn_mfma_f32_16x16x32_bf16(alo, whi, acc[m], 0, 0, 0);
            acc[m] = __builtin_amdgcn_mfma_f32_16x16x32_bf16(ahi, wlo, acc[m], 0, 0, 0);
        }
    }
    const int c  = lane & 15;
    const int r4 = (lane >> 4) * 4;
    const float bb = ba[n0 + c];
    #pragma unroll
    for (int m = 0; m < 2; ++m)
        #pragma unroll
        for (int i = 0; i < 4; ++i)
            Y[(size_t)(r0 + m * 16 + r4 + i) * DOUT + n0 + c] = acc[m][i] + bb;
}

// ---------------------------------------------------------------------------
__global__ __launch_bounds__(256) void prep_split(
    const float* __restrict__ in, unsigned short* __restrict__ hi,
    unsigned short* __restrict__ lo, int n4)
{
    int i = blockIdx.x * 256 + threadIdx.x;
    if (i < n4) {
        f32x4 v = *reinterpret_cast<const f32x4*>(in + (size_t)i * 4);
        short4v sh, sl;
        #pragma unroll
        for (int j = 0; j < 4; ++j) {
            unsigned short hb = f2bf(v[j]);
            sh[j] = (short)hb; sl[j] = (short)f2bf(v[j] - bf2f(hb));
        }
        *reinterpret_cast<short4v*>(hi + (size_t)i * 4) = sh;
        *reinterpret_cast<short4v*>(lo + (size_t)i * 4) = sl;
    }
}

// ---------------------------------------------------------------------------
extern "C" void kernel_launch(void* const* d_in, const int* in_sizes, int n_in,
                              void* d_out, int out_size, void* d_ws, size_t ws_size,
                              hipStream_t stream)
{
    const float* x  = (const float*)d_in[0];
    const float* Wl[4] = {(const float*)d_in[1], (const float*)d_in[3],
                          (const float*)d_in[5], (const float*)d_in[7]};
    const float* bl[4] = {(const float*)d_in[2], (const float*)d_in[4],
                          (const float*)d_in[6], (const float*)d_in[8]};
    const float* Wa = (const float*)d_in[9];
    const float* ba = (const float*)d_in[10];
    float* out = (float*)d_out;

    // ---- workspace carve-up ----
    char* p = (char*)d_ws;
    auto take = [&](size_t bytes) { void* q = p; p += (bytes + 255) & ~(size_t)255; return q; };
    unsigned* bar = (unsigned*)take(256);
    const size_t NX = (size_t)TT * BB * DIN;
    const size_t NH = (size_t)BB * HH;
    const size_t NC = (size_t)BB * SS;
    const size_t NO = (size_t)BB * OUTD;
    unsigned short* xHi = (unsigned short*)take(NX * 2);
    unsigned short* xLo = (unsigned short*)take(NX * 2);
    unsigned short* hHi = (unsigned short*)take(4 * TT * NH * 2);
    unsigned short* hLo = (unsigned short*)take(4 * TT * NH * 2);
    float*          cB  = (float*)take(4 * TT * NC * 4);
    unsigned short* oHi[4], *oLo[4];
    for (int l = 0; l < 4; ++l) {
        oHi[l] = (unsigned short*)take(TT * NO * 2);
        oLo[l] = (unsigned short*)take(TT * NO * 2);
    }
    float* o1F = (float*)take(TT * NO * 4);

    hipMemsetAsync(bar, 0, 8, stream);
    hipLaunchKernelGGL(prep_split, dim3((NX / 4 + 255) / 256), dim3(256), 0, stream,
                       x, xHi, xLo, (int)(NX / 4));

    const int dil[4] = {1, 2, 4, 8};
    for (int l = 0; l < 4; ++l) {
        LayerArgs la;
        la.W    = Wl[l];
        la.bias = bl[l];
        la.uHi  = (l == 0) ? xHi : oHi[l - 1];
        la.uLo  = (l == 0) ? xLo : oLo[l - 1];
        la.hHi  = hHi + (size_t)l * TT * NH;
        la.hLo  = hLo + (size_t)l * TT * NH;
        la.cB   = cB  + (size_t)l * TT * NC;
        la.outHi = oHi[l];
        la.outLo = oLo[l];
        la.o1F  = o1F;
        la.bar  = bar;
        la.Ku   = (l == 0) ? DIN : OUTD;
        la.Kin  = la.Ku + 2 * HH;
        la.dil  = dil[l];
        la.isL1 = (l == 1);
        la.isL3 = (l == 3);
        void* params[1] = {&la};
        hipLaunchCooperativeKernel((void*)layer_kernel, dim3(NBLK), dim3(512),
                                   params, 0, stream);
    }

    hipLaunchKernelGGL(adaptor_mfma, dim3(DOUT / 16, 4), dim3(512), 0, stream,
                       oHi[3], oLo[3], Wa, ba, out);
}

// Round 5
// 935.071 us; speedup vs baseline: 3.3428x; 3.3428x over previous
//
#include <hip/hip_runtime.h>

#define BB   64
#define SS   1024
#define HH   256
#define OUTD 768
#define TT   16
#define DOUT 512
#define DIN  512

typedef __attribute__((ext_vector_type(8))) short short8;
typedef __attribute__((ext_vector_type(4))) short short4v;
typedef __attribute__((ext_vector_type(4))) float f32x4;

__device__ __forceinline__ unsigned short f2bf(float f) {
    unsigned u = __builtin_bit_cast(unsigned, f);
    u += 0x7FFFu + ((u >> 16) & 1u);
    return (unsigned short)(u >> 16);
}
__device__ __forceinline__ float bf2f(unsigned short h) {
    unsigned u = ((unsigned)h) << 16;
    return __builtin_bit_cast(float, u);
}

// ---------------------------------------------------------------------------
// Fused cell phase: GEMM (split-bf16 3-pass MFMA) + block-local LSTM epilogue.
// grid = 256 blocks x 512 threads (8 waves).
// Block b owns state columns j0=b*4..+3 and ALL 4 gates for them -> the 16
// W rows {g*1024 + j0+jj}. C/D col c (lane&15) <-> row16 c = g*4+jj.
// 8-way K-split across waves, LDS reduce, epilogue entirely in-block.
// ---------------------------------------------------------------------------
__global__ __launch_bounds__(512) void cell_fused(
    const float* __restrict__ W, int Kin,
    const float* __restrict__ bias,
    const unsigned short* __restrict__ uHi, const unsigned short* __restrict__ uLo, int Ku,
    const unsigned short* __restrict__ hPrevHi, const unsigned short* __restrict__ hPrevLo,
    const unsigned short* __restrict__ hDelHi,  const unsigned short* __restrict__ hDelLo,
    const float* __restrict__ cPrev, const float* __restrict__ cDel,
    int prev_ok, int delayed_ok,
    float* __restrict__ cOut,
    unsigned short* __restrict__ outHi, unsigned short* __restrict__ outLo,
    float* __restrict__ f32out, const float* __restrict__ resid,
    unsigned short* __restrict__ hHi, unsigned short* __restrict__ hLo)
{
    __shared__ float red[32 * 272];     // [wave*4+m][(r4+i)*17 + c]
    __shared__ float Dsum[64 * 17];

    const int tid  = threadIdx.x;
    const int lane = tid & 63;
    const int w    = tid >> 6;
    const int j0   = blockIdx.x * 4;
    const int l15  = lane & 15;
    const int lk8  = (lane >> 4) * 8;

    const int Keff   = prev_ok ? Kin : Ku;
    const int Kslice = Keff >> 3;
    const int nsteps = Kslice >> 5;

    // lane's W row: row16 = l15 -> gate g = l15>>2, col j0 + (l15&3)
    const float* Wrow = W + (size_t)((l15 >> 2) * SS + j0 + (l15 & 3)) * Kin + lk8;

    f32x4 acc[4] = {{0,0,0,0},{0,0,0,0},{0,0,0,0},{0,0,0,0}};
    int kb = w * Kslice;
    for (int s = 0; s < nsteps; ++s, kb += 32) {
        // W frag (8 fp32) -> hi/lo bf16 on the fly
        f32x4 wv0 = *reinterpret_cast<const f32x4*>(Wrow + kb);
        f32x4 wv1 = *reinterpret_cast<const f32x4*>(Wrow + kb + 4);
        short8 whi, wlo;
        #pragma unroll
        for (int q = 0; q < 4; ++q) {
            unsigned short hb = f2bf(wv0[q]);
            whi[q] = (short)hb; wlo[q] = (short)f2bf(wv0[q] - bf2f(hb));
            unsigned short hb2 = f2bf(wv1[q]);
            whi[4+q] = (short)hb2; wlo[4+q] = (short)f2bf(wv1[q] - bf2f(hb2));
        }
        // A segment resolve (wave-uniform kb)
        const unsigned short *pHi, *pLo; int stride, koff;
        if (kb < Ku)           { pHi = uHi;     pLo = uLo;     stride = Ku; koff = kb; }
        else if (kb < Ku + HH) { pHi = hPrevHi; pLo = hPrevLo; stride = HH; koff = kb - Ku; }
        else                   { pHi = hDelHi;  pLo = hDelLo;  stride = HH; koff = kb - Ku - HH; }
        const int ao = koff + lk8;
        #pragma unroll
        for (int m = 0; m < 4; ++m) {
            const int r = m * 16 + l15;
            short8 ahi = *reinterpret_cast<const short8*>(pHi + (size_t)r * stride + ao);
            short8 alo = *reinterpret_cast<const short8*>(pLo + (size_t)r * stride + ao);
            acc[m] = __builtin_amdgcn_mfma_f32_16x16x32_bf16(ahi, whi, acc[m], 0, 0, 0);
            acc[m] = __builtin_amdgcn_mfma_f32_16x16x32_bf16(alo, whi, acc[m], 0, 0, 0);
            acc[m] = __builtin_amdgcn_mfma_f32_16x16x32_bf16(ahi, wlo, acc[m], 0, 0, 0);
        }
    }

    // partials -> LDS (C/D layout: col = lane&15, row = (lane>>4)*4 + i)
    {
        const int c  = lane & 15;
        const int r4 = (lane >> 4) * 4;
        #pragma unroll
        for (int m = 0; m < 4; ++m)
            #pragma unroll
            for (int i = 0; i < 4; ++i)
                red[(w * 4 + m) * 272 + (r4 + i) * 17 + c] = acc[m][i];
    }
    __syncthreads();

    // cross-wave reduce: 1024 outputs, 2 per thread
    #pragma unroll
    for (int e2 = 0; e2 < 2; ++e2) {
        const int e  = tid + e2 * 512;
        const int m  = e >> 8;
        const int rr = (e >> 4) & 15;
        const int c  = e & 15;
        float sum = 0.f;
        #pragma unroll
        for (int w2 = 0; w2 < 8; ++w2)
            sum += red[(w2 * 4 + m) * 272 + rr * 17 + c];
        Dsum[(m * 16 + rr) * 17 + c] = sum;
    }
    __syncthreads();

    // block-local LSTM epilogue: 64 rows x 4 cols (threads 0..255)
    if (tid < 256) {
        const int r  = tid >> 2;
        const int jj = tid & 3;
        const int j  = j0 + jj;
        float g0 = Dsum[r * 17 + 0  + jj] + bias[j];
        float g1 = Dsum[r * 17 + 4  + jj] + bias[SS + j];
        float g2 = Dsum[r * 17 + 8  + jj] + bias[2 * SS + j];
        float g3 = Dsum[r * 17 + 12 + jj] + bias[3 * SS + j];

        float f  = 1.f / (1.f + __expf(-(g0 + 1.f)));
        float n  = tanhf(g1);
        float av = 1.f / (1.f + __expf(-g2));
        float o  = 1.f / (1.f + __expf(-g3));

        float pC = prev_ok ? cPrev[(size_t)r * SS + j] : 0.f;
        float dC = delayed_ok ? cDel[(size_t)r * SS + j] : pC;
        float wC = delayed_ok ? (av * pC + (1.f - av) * dC) : pC;
        float nf = prev_ok ? (f * wC + (1.f - f) * n) : n;
        float wh = o * nf;

        cOut[(size_t)r * SS + j] = nf;

        if (j < OUTD) {
            float v = wh;
            const size_t oidx = (size_t)r * OUTD + j;
            if (resid)  v += resid[oidx];
            if (f32out) f32out[oidx] = v;
            unsigned short hb = f2bf(v);
            outHi[oidx] = hb;
            outLo[oidx] = f2bf(v - bf2f(hb));
        } else {
            const int jo = j - OUTD;
            const size_t hidx = (size_t)r * HH + jo;
            unsigned short hb = f2bf(wh);
            hHi[hidx] = hb;
            hLo[hidx] = f2bf(wh - bf2f(hb));
        }
    }
}

// ---------------------------------------------------------------------------
// Adaptor: Y[1024][512] = A[1024][768] @ Wa[512][768]^T + ba, 3-pass MFMA.
// ---------------------------------------------------------------------------
__global__ __launch_bounds__(512) void adaptor_mfma(
    const unsigned short* __restrict__ Ahi, const unsigned short* __restrict__ Alo,
    const float* __restrict__ Wa, const float* __restrict__ ba,
    float* __restrict__ Y)
{
    const int tid  = threadIdx.x;
    const int lane = tid & 63;
    const int w    = tid >> 6;
    const int n0   = blockIdx.x * 16;
    const int r0   = blockIdx.y * 256 + w * 32;
    const int l15  = lane & 15;
    const int lk8  = (lane >> 4) * 8;

    f32x4 acc[2] = {{0,0,0,0},{0,0,0,0}};
    const float* Wrow = Wa + (size_t)(n0 + l15) * OUTD + lk8;
    for (int kb = 0; kb < OUTD; kb += 32) {
        f32x4 wv0 = *reinterpret_cast<const f32x4*>(Wrow + kb);
        f32x4 wv1 = *reinterpret_cast<const f32x4*>(Wrow + kb + 4);
        short8 whi, wlo;
        #pragma unroll
        for (int q = 0; q < 4; ++q) {
            unsigned short hb = f2bf(wv0[q]);
            whi[q] = (short)hb; wlo[q] = (short)f2bf(wv0[q] - bf2f(hb));
            unsigned short hb2 = f2bf(wv1[q]);
            whi[4+q] = (short)hb2; wlo[4+q] = (short)f2bf(wv1[q] - bf2f(hb2));
        }
        #pragma unroll
        for (int m = 0; m < 2; ++m) {
            const int r = r0 + m * 16 + l15;
            short8 ahi = *reinterpret_cast<const short8*>(Ahi + (size_t)r * OUTD + kb + lk8);
            short8 alo = *reinterpret_cast<const short8*>(Alo + (size_t)r * OUTD + kb + lk8);
            acc[m] = __builtin_amdgcn_mfma_f32_16x16x32_bf16(ahi, whi, acc[m], 0, 0, 0);
            acc[m] = __builtin_amdgcn_mfma_f32_16x16x32_bf16(alo, whi, acc[m], 0, 0, 0);
            acc[m] = __builtin_amdgcn_mfma_f32_16x16x32_bf16(ahi, wlo, acc[m], 0, 0, 0);
        }
    }
    const int c  = lane & 15;
    const int r4 = (lane >> 4) * 4;
    const float bb = ba[n0 + c];
    #pragma unroll
    for (int m = 0; m < 2; ++m)
        #pragma unroll
        for (int i = 0; i < 4; ++i)
            Y[(size_t)(r0 + m * 16 + r4 + i) * DOUT + n0 + c] = acc[m][i] + bb;
}

// ---------------------------------------------------------------------------
__global__ __launch_bounds__(256) void prep_split(
    const float* __restrict__ in, unsigned short* __restrict__ hi,
    unsigned short* __restrict__ lo, int n4)
{
    int i = blockIdx.x * 256 + threadIdx.x;
    if (i < n4) {
        f32x4 v = *reinterpret_cast<const f32x4*>(in + (size_t)i * 4);
        short4v sh, sl;
        #pragma unroll
        for (int j = 0; j < 4; ++j) {
            unsigned short hb = f2bf(v[j]);
            sh[j] = (short)hb; sl[j] = (short)f2bf(v[j] - bf2f(hb));
        }
        *reinterpret_cast<short4v*>(hi + (size_t)i * 4) = sh;
        *reinterpret_cast<short4v*>(lo + (size_t)i * 4) = sl;
    }
}

// ---------------------------------------------------------------------------
extern "C" void kernel_launch(void* const* d_in, const int* in_sizes, int n_in,
                              void* d_out, int out_size, void* d_ws, size_t ws_size,
                              hipStream_t stream)
{
    const float* x  = (const float*)d_in[0];
    const float* Wl[4] = {(const float*)d_in[1], (const float*)d_in[3],
                          (const float*)d_in[5], (const float*)d_in[7]};
    const float* bl[4] = {(const float*)d_in[2], (const float*)d_in[4],
                          (const float*)d_in[6], (const float*)d_in[8]};
    const float* Wa = (const float*)d_in[9];
    const float* ba = (const float*)d_in[10];
    float* out = (float*)d_out;

    // ---- workspace carve-up ----
    char* p = (char*)d_ws;
    auto take = [&](size_t bytes) { void* q = p; p += (bytes + 255) & ~(size_t)255; return q; };
    const size_t NX = (size_t)TT * BB * DIN;
    const size_t NH = (size_t)BB * HH;
    const size_t NC = (size_t)BB * SS;
    const size_t NO = (size_t)BB * OUTD;
    unsigned short* xHi = (unsigned short*)take(NX * 2);
    unsigned short* xLo = (unsigned short*)take(NX * 2);
    unsigned short* hHi = (unsigned short*)take(4 * TT * NH * 2);
    unsigned short* hLo = (unsigned short*)take(4 * TT * NH * 2);
    float*          cB  = (float*)take(4 * TT * NC * 4);
    unsigned short* oHi[4], *oLo[4];
    for (int l = 0; l < 4; ++l) {
        oHi[l] = (unsigned short*)take(TT * NO * 2);
        oLo[l] = (unsigned short*)take(TT * NO * 2);
    }
    float* o1F = (float*)take(TT * NO * 4);

    hipLaunchKernelGGL(prep_split, dim3((NX / 4 + 255) / 256), dim3(256), 0, stream,
                       x, xHi, xLo, (int)(NX / 4));

    const int dil[4] = {1, 2, 4, 8};
    for (int l = 0; l < 4; ++l) {
        const int Ku  = (l == 0) ? DIN : OUTD;
        const int Kin = Ku + 2 * HH;
        const unsigned short* uHiL = (l == 0) ? xHi : oHi[l - 1];
        const unsigned short* uLoL = (l == 0) ? xLo : oLo[l - 1];
        unsigned short* hHl = hHi + (size_t)l * TT * NH;
        unsigned short* hLl = hLo + (size_t)l * TT * NH;
        float* cL = cB + (size_t)l * TT * NC;

        for (int t = 0; t < TT; ++t) {
            const int prev_ok    = (t > 0);
            const int d          = dil[l];
            const int delayed_ok = (t >= d);
            const int tm1 = prev_ok ? t - 1 : 0;
            const int td  = delayed_ok ? t - d : tm1;

            float* f32out = (l == 1) ? (o1F + (size_t)t * NO) : nullptr;
            const float* resid = (l == 3) ? (o1F + (size_t)t * NO) : nullptr;

            hipLaunchKernelGGL(cell_fused, dim3(256), dim3(512), 0, stream,
                Wl[l], Kin, bl[l],
                uHiL + (size_t)t * BB * Ku, uLoL + (size_t)t * BB * Ku, Ku,
                hHl + (size_t)tm1 * NH, hLl + (size_t)tm1 * NH,
                hHl + (size_t)td  * NH, hLl + (size_t)td  * NH,
                cL + (size_t)tm1 * NC, cL + (size_t)td * NC,
                prev_ok, delayed_ok,
                cL + (size_t)t * NC,
                oHi[l] + (size_t)t * NO, oLo[l] + (size_t)t * NO,
                f32out, resid,
                hHl + (size_t)t * NH, hLl + (size_t)t * NH);
        }
    }

    hipLaunchKernelGGL(adaptor_mfma, dim3(DOUT / 16, 4), dim3(512), 0, stream,
                       oHi[3], oLo[3], Wa, ba, out);
}

// Round 6
// 777.527 us; speedup vs baseline: 4.0202x; 1.2026x over previous
//
#include <hip/hip_runtime.h>

#define BB   64
#define SS   1024
#define HH   256
#define OUTD 768
#define TT   16
#define DOUT 512
#define DIN  512

typedef __attribute__((ext_vector_type(8))) short short8;
typedef __attribute__((ext_vector_type(4))) short short4v;
typedef __attribute__((ext_vector_type(4))) float f32x4;

__device__ __forceinline__ unsigned short f2bf(float f) {
    unsigned u = __builtin_bit_cast(unsigned, f);
    u += 0x7FFFu + ((u >> 16) & 1u);
    return (unsigned short)(u >> 16);
}
__device__ __forceinline__ float bf2f(unsigned short h) {
    unsigned u = ((unsigned)h) << 16;
    return __builtin_bit_cast(float, u);
}

// ---------------------------------------------------------------------------
// Per-cell descriptor for the wavefront kernel.
// ---------------------------------------------------------------------------
struct CellDesc {
    const unsigned short *WrHi, *WrLo;   // reordered W: [strip][stepFull][lane][8]
    const float* bias;
    const unsigned short *uHi, *uLo;
    const unsigned short *hPrevHi, *hPrevLo, *hDelHi, *hDelLo;
    const float *cPrev, *cDel;
    float* cOut;
    unsigned short *outHi, *outLo;
    float* f32out;
    const float* resid;
    unsigned short *hHi, *hLo;
    int Ku, Kin, prev_ok, delayed_ok, nstepsFull, pad;
};
struct StepArgs { CellDesc c[4]; };

// ---------------------------------------------------------------------------
// Wavefront cell kernel: grid = nCells*256 blocks x 512 thr (8 waves).
// Block (cellIdx, strip): strip owns state cols j0=strip*4 and all 4 gates
// (16 W rows). 8-way K-split across waves, LDS reduce, block-local epilogue.
// W read from pre-reordered bf16 hi/lo (perfectly coalesced, no conversion).
// ---------------------------------------------------------------------------
__global__ __launch_bounds__(512) void cell_wave(StepArgs sa)
{
    __shared__ float red[32 * 272];
    __shared__ float Dsum[64 * 17];

    const int cellIdx = blockIdx.x >> 8;
    const int strip   = blockIdx.x & 255;
    const CellDesc& a = sa.c[cellIdx];

    const int tid  = threadIdx.x;
    const int lane = tid & 63;
    const int w    = tid >> 6;
    const int j0   = strip * 4;
    const int l15  = lane & 15;
    const int lk8  = (lane >> 4) * 8;

    const int Ku     = a.Ku;
    const int Keff   = a.prev_ok ? a.Kin : a.Ku;
    const int Kslice = Keff >> 3;
    const int nsteps = Kslice >> 5;

    const size_t wbase =
        (((size_t)strip * a.nstepsFull + (w * Kslice >> 5)) * 64 + lane) * 8;
    const unsigned short* wh = a.WrHi + wbase;
    const unsigned short* wl = a.WrLo + wbase;

    f32x4 acc[4] = {{0,0,0,0},{0,0,0,0},{0,0,0,0},{0,0,0,0}};
    int kb = w * Kslice;
    for (int s = 0; s < nsteps; ++s, kb += 32) {
        short8 whi = *reinterpret_cast<const short8*>(wh + (size_t)s * 512);
        short8 wlo = *reinterpret_cast<const short8*>(wl + (size_t)s * 512);
        const unsigned short *pHi, *pLo; int stride, koff;
        if (kb < Ku)           { pHi = a.uHi;     pLo = a.uLo;     stride = Ku; koff = kb; }
        else if (kb < Ku + HH) { pHi = a.hPrevHi; pLo = a.hPrevLo; stride = HH; koff = kb - Ku; }
        else                   { pHi = a.hDelHi;  pLo = a.hDelLo;  stride = HH; koff = kb - Ku - HH; }
        const int ao = koff + lk8;
        #pragma unroll
        for (int m = 0; m < 4; ++m) {
            const int r = m * 16 + l15;
            short8 ahi = *reinterpret_cast<const short8*>(pHi + (size_t)r * stride + ao);
            short8 alo = *reinterpret_cast<const short8*>(pLo + (size_t)r * stride + ao);
            acc[m] = __builtin_amdgcn_mfma_f32_16x16x32_bf16(ahi, whi, acc[m], 0, 0, 0);
            acc[m] = __builtin_amdgcn_mfma_f32_16x16x32_bf16(alo, whi, acc[m], 0, 0, 0);
            acc[m] = __builtin_amdgcn_mfma_f32_16x16x32_bf16(ahi, wlo, acc[m], 0, 0, 0);
        }
    }

    // partials -> LDS (C/D layout: col = lane&15, row = (lane>>4)*4 + i)
    {
        const int c  = lane & 15;
        const int r4 = (lane >> 4) * 4;
        #pragma unroll
        for (int m = 0; m < 4; ++m)
            #pragma unroll
            for (int i = 0; i < 4; ++i)
                red[(w * 4 + m) * 272 + (r4 + i) * 17 + c] = acc[m][i];
    }
    __syncthreads();

    #pragma unroll
    for (int e2 = 0; e2 < 2; ++e2) {
        const int e  = tid + e2 * 512;
        const int m  = e >> 8;
        const int rr = (e >> 4) & 15;
        const int c  = e & 15;
        float sum = 0.f;
        #pragma unroll
        for (int w2 = 0; w2 < 8; ++w2)
            sum += red[(w2 * 4 + m) * 272 + rr * 17 + c];
        Dsum[(m * 16 + rr) * 17 + c] = sum;
    }
    __syncthreads();

    // block-local LSTM epilogue: 64 rows x 4 cols (threads 0..255)
    if (tid < 256) {
        const int r  = tid >> 2;
        const int jj = tid & 3;
        const int j  = j0 + jj;
        float g0 = Dsum[r * 17 + 0  + jj] + a.bias[j];
        float g1 = Dsum[r * 17 + 4  + jj] + a.bias[SS + j];
        float g2 = Dsum[r * 17 + 8  + jj] + a.bias[2 * SS + j];
        float g3 = Dsum[r * 17 + 12 + jj] + a.bias[3 * SS + j];

        float f  = 1.f / (1.f + __expf(-(g0 + 1.f)));
        float n  = tanhf(g1);
        float av = 1.f / (1.f + __expf(-g2));
        float o  = 1.f / (1.f + __expf(-g3));

        float pC = a.prev_ok ? a.cPrev[(size_t)r * SS + j] : 0.f;
        float dC = a.delayed_ok ? a.cDel[(size_t)r * SS + j] : pC;
        float wC = a.delayed_ok ? (av * pC + (1.f - av) * dC) : pC;
        float nf = a.prev_ok ? (f * wC + (1.f - f) * n) : n;
        float wh2 = o * nf;

        a.cOut[(size_t)r * SS + j] = nf;

        if (j < OUTD) {
            float v = wh2;
            const size_t oidx = (size_t)r * OUTD + j;
            if (a.resid)  v += a.resid[oidx];
            if (a.f32out) a.f32out[oidx] = v;
            unsigned short hb = f2bf(v);
            a.outHi[oidx] = hb;
            a.outLo[oidx] = f2bf(v - bf2f(hb));
        } else {
            const int jo = j - OUTD;
            const size_t hidx = (size_t)r * HH + jo;
            unsigned short hb = f2bf(wh2);
            a.hHi[hidx] = hb;
            a.hLo[hidx] = f2bf(wh2 - bf2f(hb));
        }
    }
}

// ---------------------------------------------------------------------------
// W reorder: fp32 [4096][Kin] -> bf16 hi/lo in fragment order
// [strip=256][step][lane=64][8], where row16 = lane&15 -> W row
// (row16>>2)*1024 + strip*4 + (row16&3); k = step*32 + (lane>>4)*8.
// ---------------------------------------------------------------------------
__global__ __launch_bounds__(256) void prep_reorderW(
    const float* __restrict__ W, int Kin, int nsteps,
    unsigned short* __restrict__ WrHi, unsigned short* __restrict__ WrLo)
{
    const int p    = blockIdx.x;
    const int lane = threadIdx.x & 63;
    const int sq   = threadIdx.x >> 6;
    const int s    = blockIdx.y * 4 + sq;
    if (s >= nsteps) return;
    const int r16  = lane & 15;
    const int row  = (r16 >> 2) * SS + p * 4 + (r16 & 3);
    const int k    = s * 32 + (lane >> 4) * 8;

    f32x4 v0 = *reinterpret_cast<const f32x4*>(W + (size_t)row * Kin + k);
    f32x4 v1 = *reinterpret_cast<const f32x4*>(W + (size_t)row * Kin + k + 4);
    short8 hi, lo;
    #pragma unroll
    for (int q = 0; q < 4; ++q) {
        unsigned short hb = f2bf(v0[q]);
        hi[q] = (short)hb; lo[q] = (short)f2bf(v0[q] - bf2f(hb));
        unsigned short hb2 = f2bf(v1[q]);
        hi[4+q] = (short)hb2; lo[4+q] = (short)f2bf(v1[q] - bf2f(hb2));
    }
    const size_t off = (((size_t)p * nsteps + s) * 64 + lane) * 8;
    *reinterpret_cast<short8*>(WrHi + off) = hi;
    *reinterpret_cast<short8*>(WrLo + off) = lo;
}

// ---------------------------------------------------------------------------
// Adaptor: Y[1024][512] = A[1024][768] @ Wa[512][768]^T + ba, 3-pass MFMA.
// ---------------------------------------------------------------------------
__global__ __launch_bounds__(512) void adaptor_mfma(
    const unsigned short* __restrict__ Ahi, const unsigned short* __restrict__ Alo,
    const float* __restrict__ Wa, const float* __restrict__ ba,
    float* __restrict__ Y)
{
    const int tid  = threadIdx.x;
    const int lane = tid & 63;
    const int w    = tid >> 6;
    const int n0   = blockIdx.x * 16;
    const int r0   = blockIdx.y * 256 + w * 32;
    const int l15  = lane & 15;
    const int lk8  = (lane >> 4) * 8;

    f32x4 acc[2] = {{0,0,0,0},{0,0,0,0}};
    const float* Wrow = Wa + (size_t)(n0 + l15) * OUTD + lk8;
    for (int kb = 0; kb < OUTD; kb += 32) {
        f32x4 wv0 = *reinterpret_cast<const f32x4*>(Wrow + kb);
        f32x4 wv1 = *reinterpret_cast<const f32x4*>(Wrow + kb + 4);
        short8 whi, wlo;
        #pragma unroll
        for (int q = 0; q < 4; ++q) {
            unsigned short hb = f2bf(wv0[q]);
            whi[q] = (short)hb; wlo[q] = (short)f2bf(wv0[q] - bf2f(hb));
            unsigned short hb2 = f2bf(wv1[q]);
            whi[4+q] = (short)hb2; wlo[4+q] = (short)f2bf(wv1[q] - bf2f(hb2));
        }
        #pragma unroll
        for (int m = 0; m < 2; ++m) {
            const int r = r0 + m * 16 + l15;
            short8 ahi = *reinterpret_cast<const short8*>(Ahi + (size_t)r * OUTD + kb + lk8);
            short8 alo = *reinterpret_cast<const short8*>(Alo + (size_t)r * OUTD + kb + lk8);
            acc[m] = __builtin_amdgcn_mfma_f32_16x16x32_bf16(ahi, whi, acc[m], 0, 0, 0);
            acc[m] = __builtin_amdgcn_mfma_f32_16x16x32_bf16(alo, whi, acc[m], 0, 0, 0);
            acc[m] = __builtin_amdgcn_mfma_f32_16x16x32_bf16(ahi, wlo, acc[m], 0, 0, 0);
        }
    }
    const int c  = lane & 15;
    const int r4 = (lane >> 4) * 4;
    const float bb = ba[n0 + c];
    #pragma unroll
    for (int m = 0; m < 2; ++m)
        #pragma unroll
        for (int i = 0; i < 4; ++i)
            Y[(size_t)(r0 + m * 16 + r4 + i) * DOUT + n0 + c] = acc[m][i] + bb;
}

// ---------------------------------------------------------------------------
__global__ __launch_bounds__(256) void prep_split(
    const float* __restrict__ in, unsigned short* __restrict__ hi,
    unsigned short* __restrict__ lo, int n4)
{
    int i = blockIdx.x * 256 + threadIdx.x;
    if (i < n4) {
        f32x4 v = *reinterpret_cast<const f32x4*>(in + (size_t)i * 4);
        short4v sh, sl;
        #pragma unroll
        for (int j = 0; j < 4; ++j) {
            unsigned short hb = f2bf(v[j]);
            sh[j] = (short)hb; sl[j] = (short)f2bf(v[j] - bf2f(hb));
        }
        *reinterpret_cast<short4v*>(hi + (size_t)i * 4) = sh;
        *reinterpret_cast<short4v*>(lo + (size_t)i * 4) = sl;
    }
}

// ---------------------------------------------------------------------------
extern "C" void kernel_launch(void* const* d_in, const int* in_sizes, int n_in,
                              void* d_out, int out_size, void* d_ws, size_t ws_size,
                              hipStream_t stream)
{
    const float* x  = (const float*)d_in[0];
    const float* Wl[4] = {(const float*)d_in[1], (const float*)d_in[3],
                          (const float*)d_in[5], (const float*)d_in[7]};
    const float* bl[4] = {(const float*)d_in[2], (const float*)d_in[4],
                          (const float*)d_in[6], (const float*)d_in[8]};
    const float* Wa = (const float*)d_in[9];
    const float* ba = (const float*)d_in[10];
    float* out = (float*)d_out;

    // ---- workspace carve-up ----
    char* p = (char*)d_ws;
    auto take = [&](size_t bytes) { void* q = p; p += (bytes + 255) & ~(size_t)255; return q; };
    const size_t NX = (size_t)TT * BB * DIN;
    const size_t NH = (size_t)BB * HH;
    const size_t NC = (size_t)BB * SS;
    const size_t NO = (size_t)BB * OUTD;
    unsigned short* xHi = (unsigned short*)take(NX * 2);
    unsigned short* xLo = (unsigned short*)take(NX * 2);
    unsigned short* hHi = (unsigned short*)take(4 * TT * NH * 2);
    unsigned short* hLo = (unsigned short*)take(4 * TT * NH * 2);
    float*          cB  = (float*)take(4 * TT * NC * 4);
    unsigned short* oHi[4], *oLo[4];
    for (int l = 0; l < 4; ++l) {
        oHi[l] = (unsigned short*)take(TT * NO * 2);
        oLo[l] = (unsigned short*)take(TT * NO * 2);
    }
    float* o1F = (float*)take(TT * NO * 4);
    unsigned short *WrHi[4], *WrLo[4];
    const int Kus[4]  = {DIN, OUTD, OUTD, OUTD};
    const int dil[4]  = {1, 2, 4, 8};
    int Kins[4], nstepsF[4];
    for (int l = 0; l < 4; ++l) {
        Kins[l]   = Kus[l] + 2 * HH;
        nstepsF[l] = Kins[l] / 32;
        size_t n = (size_t)4 * SS * Kins[l];        // 4096 * Kin elems
        WrHi[l] = (unsigned short*)take(n * 2);
        WrLo[l] = (unsigned short*)take(n * 2);
    }

    // ---- prep: input split + W reorders ----
    hipLaunchKernelGGL(prep_split, dim3((NX / 4 + 255) / 256), dim3(256), 0, stream,
                       x, xHi, xLo, (int)(NX / 4));
    for (int l = 0; l < 4; ++l) {
        hipLaunchKernelGGL(prep_reorderW, dim3(256, (nstepsF[l] + 3) / 4), dim3(256),
                           0, stream, Wl[l], Kins[l], nstepsF[l], WrHi[l], WrLo[l]);
    }

    // ---- wavefront: step s runs all cells (l, t=s-l) ----
    for (int s = 0; s <= TT - 1 + 3; ++s) {
        StepArgs sa;
        int n = 0;
        for (int l = 0; l < 4; ++l) {
            const int t = s - l;
            if (t < 0 || t >= TT) continue;
            CellDesc& d = sa.c[n++];
            const int Ku = Kus[l];
            const int prev_ok    = (t > 0);
            const int delayed_ok = (t >= dil[l]);
            const int tm1 = prev_ok ? t - 1 : 0;
            const int td  = delayed_ok ? t - dil[l] : tm1;
            const unsigned short* uHiL = (l == 0) ? xHi : oHi[l - 1];
            const unsigned short* uLoL = (l == 0) ? xLo : oLo[l - 1];
            unsigned short* hHl = hHi + (size_t)l * TT * NH;
            unsigned short* hLl = hLo + (size_t)l * TT * NH;
            float* cL = cB + (size_t)l * TT * NC;

            d.WrHi = WrHi[l]; d.WrLo = WrLo[l];
            d.bias = bl[l];
            d.uHi = uHiL + (size_t)t * BB * Ku;
            d.uLo = uLoL + (size_t)t * BB * Ku;
            d.hPrevHi = hHl + (size_t)tm1 * NH;
            d.hPrevLo = hLl + (size_t)tm1 * NH;
            d.hDelHi  = hHl + (size_t)td  * NH;
            d.hDelLo  = hLl + (size_t)td  * NH;
            d.cPrev = cL + (size_t)tm1 * NC;
            d.cDel  = cL + (size_t)td  * NC;
            d.cOut  = cL + (size_t)t   * NC;
            d.outHi = oHi[l] + (size_t)t * NO;
            d.outLo = oLo[l] + (size_t)t * NO;
            d.f32out = (l == 1) ? (o1F + (size_t)t * NO) : nullptr;
            d.resid  = (l == 3) ? (o1F + (size_t)t * NO) : nullptr;
            d.hHi = hHl + (size_t)t * NH;
            d.hLo = hLl + (size_t)t * NH;
            d.Ku = Ku; d.Kin = Kins[l];
            d.prev_ok = prev_ok; d.delayed_ok = delayed_ok;
            d.nstepsFull = nstepsF[l]; d.pad = 0;
        }
        hipLaunchKernelGGL(cell_wave, dim3(n * 256), dim3(512), 0, stream, sa);
    }

    hipLaunchKernelGGL(adaptor_mfma, dim3(DOUT / 16, 4), dim3(512), 0, stream,
                       oHi[3], oLo[3], Wa, ba, out);
}

// Round 8
// 434.836 us; speedup vs baseline: 7.1884x; 1.7881x over previous
//
// Resubmit of round-6 kernel (container died before bench; no signal to act on).
#include <hip/hip_runtime.h>

#define BB   64
#define SS   1024
#define HH   256
#define OUTD 768
#define TT   16
#define DOUT 512
#define DIN  512

typedef __attribute__((ext_vector_type(8))) short short8;
typedef __attribute__((ext_vector_type(4))) short short4v;
typedef __attribute__((ext_vector_type(4))) float f32x4;

__device__ __forceinline__ unsigned short f2bf(float f) {
    unsigned u = __builtin_bit_cast(unsigned, f);
    u += 0x7FFFu + ((u >> 16) & 1u);
    return (unsigned short)(u >> 16);
}
__device__ __forceinline__ float bf2f(unsigned short h) {
    unsigned u = ((unsigned)h) << 16;
    return __builtin_bit_cast(float, u);
}

// ---------------------------------------------------------------------------
struct CellDesc {
    const unsigned short* Wr;        // [strip64][plane2][step32][gate4][lane64][8]
    const float* bias;
    const unsigned short *uHi, *uLo;
    const unsigned short *hPrevHi, *hPrevLo, *hDelHi, *hDelLo;
    const float *cPrev, *cDel;
    float* cOut;
    unsigned short *outHi, *outLo;
    float* f32out;
    const float* resid;
    unsigned short *hHi, *hLo;
    int Ku, Kin, prev_ok, delayed_ok, nst32, pad;
};
struct StepArgs { CellDesc c[4]; };

// ---------------------------------------------------------------------------
// Tiled wavefront cell kernel. grid = nCells*64 blocks x 512 thr (8 waves).
// Block (cell, strip): output tile = 64 rows x (16 state cols x 4 gates).
// Waves (wm 2 x wn 4): wave = 32 rows x 16 cols of gate wn (2 m-frags).
// K-loop: BK=64 per step, A+W double-buffered in LDS, 1 barrier/step.
// Epilogue: gate-gather via Csum LDS, LSTM math block-local.
// ---------------------------------------------------------------------------
__global__ __launch_bounds__(512, 1) void cell_wave(StepArgs sa)
{
    __shared__ unsigned short Alds[2][2 * 64 * 72];       // [buf][p*4608 + row*72 + k]
    __shared__ unsigned short Wlds[2][2 * 2 * 4 * 64 * 8];// [buf][((p*2+kk)*4+g)*512 + l*8]
    __shared__ float Csum[64 * 68];                        // [n=g*16+jj][row], pitch 68

    const int cellIdx = blockIdx.x >> 6;
    const int strip   = blockIdx.x & 63;
    const CellDesc& a = sa.c[cellIdx];

    const int tid  = threadIdx.x;
    const int lane = tid & 63;
    const int w    = tid >> 6;
    const int wm   = w >> 2;          // 0..1 (row half)
    const int wn   = w & 3;           // gate
    const int l15  = lane & 15;
    const int lk8  = (lane >> 4) * 8;

    const int Ku    = a.Ku;
    const int nst32 = a.nst32;
    const int nst64 = (a.prev_ok ? a.Kin : a.Ku) >> 6;

    // staging thread mapping (constant)
    const int ar  = tid >> 3, as8 = tid & 7;            // A: row, k-oct
    const int wkk = (tid >> 8) & 1, wg = (tid >> 6) & 3, wl = tid & 63;  // W chunk
    const int aoff = ar * 72 + as8 * 8;                  // shorts, plane 0
    const int woff = (wkk * 4 + wg) * 512 + wl * 8;      // shorts, plane 0

    f32x4 rA0, rA1, rW0, rW1;
    auto stageLoad = [&](int S) {
        const int kb = S * 64;
        const unsigned short *sHi, *sLo; int stride, koff;
        if (kb < Ku)           { sHi = a.uHi;     sLo = a.uLo;     stride = Ku; koff = kb; }
        else if (kb < Ku + HH) { sHi = a.hPrevHi; sLo = a.hPrevLo; stride = HH; koff = kb - Ku; }
        else                   { sHi = a.hDelHi;  sLo = a.hDelLo;  stride = HH; koff = kb - Ku - HH; }
        rA0 = *(const f32x4*)(sHi + (size_t)ar * stride + koff + as8 * 8);
        rA1 = *(const f32x4*)(sLo + (size_t)ar * stride + koff + as8 * 8);
        const size_t wb0 = ((((size_t)strip * 2 + 0) * nst32 + (2 * S + wkk)) * 4 + wg) * 512 + (size_t)wl * 8;
        const size_t wb1 = ((((size_t)strip * 2 + 1) * nst32 + (2 * S + wkk)) * 4 + wg) * 512 + (size_t)wl * 8;
        rW0 = *(const f32x4*)(a.Wr + wb0);
        rW1 = *(const f32x4*)(a.Wr + wb1);
    };
    auto stageWrite = [&](int nb) {
        *(f32x4*)&Alds[nb][aoff]        = rA0;
        *(f32x4*)&Alds[nb][4608 + aoff] = rA1;
        *(f32x4*)&Wlds[nb][woff]        = rW0;
        *(f32x4*)&Wlds[nb][4096 + woff] = rW1;
    };

    f32x4 acc[2] = {{0,0,0,0},{0,0,0,0}};

    // prologue: stage step 0 into buf 0
    stageLoad(0);
    stageWrite(0);
    __syncthreads();

    int cur = 0;
    for (int S = 0; S < nst64; ++S) {
        const int nb = cur ^ 1;
        const bool more = (S + 1 < nst64);
        if (more) stageLoad(S + 1);

        #pragma unroll
        for (int kk = 0; kk < 2; ++kk) {
            short8 whi = *(const short8*)&Wlds[cur][(kk * 4 + wn) * 512 + lane * 8];
            short8 wlo = *(const short8*)&Wlds[cur][4096 + (kk * 4 + wn) * 512 + lane * 8];
            #pragma unroll
            for (int mm = 0; mm < 2; ++mm) {
                const int row = wm * 32 + mm * 16 + l15;
                short8 ahi = *(const short8*)&Alds[cur][row * 72 + kk * 32 + lk8];
                short8 alo = *(const short8*)&Alds[cur][4608 + row * 72 + kk * 32 + lk8];
                acc[mm] = __builtin_amdgcn_mfma_f32_16x16x32_bf16(ahi, whi, acc[mm], 0, 0, 0);
                acc[mm] = __builtin_amdgcn_mfma_f32_16x16x32_bf16(alo, whi, acc[mm], 0, 0, 0);
                acc[mm] = __builtin_amdgcn_mfma_f32_16x16x32_bf16(ahi, wlo, acc[mm], 0, 0, 0);
            }
        }
        if (more) stageWrite(nb);
        __syncthreads();
        cur = nb;
    }

    // C frags -> Csum  (frag: col c=lane&15 -> n = wn*16+c; row = wm*32+mm*16+(lane>>4)*4+i)
    {
        const int c  = lane & 15;
        const int r4 = (lane >> 4) * 4;
        #pragma unroll
        for (int mm = 0; mm < 2; ++mm)
            *(f32x4*)&Csum[(wn * 16 + c) * 68 + wm * 32 + mm * 16 + r4] = acc[mm];
    }
    __syncthreads();

    // block-local LSTM epilogue: 64 rows x 16 cols, 2 per thread
    #pragma unroll
    for (int e2 = 0; e2 < 2; ++e2) {
        const int idx = tid + e2 * 512;
        const int r   = idx >> 4;
        const int jj  = idx & 15;
        const int j   = strip * 16 + jj;
        float g0 = Csum[(0  + jj) * 68 + r] + a.bias[j];
        float g1 = Csum[(16 + jj) * 68 + r] + a.bias[SS + j];
        float g2 = Csum[(32 + jj) * 68 + r] + a.bias[2 * SS + j];
        float g3 = Csum[(48 + jj) * 68 + r] + a.bias[3 * SS + j];

        float f  = 1.f / (1.f + __expf(-(g0 + 1.f)));
        float n  = tanhf(g1);
        float av = 1.f / (1.f + __expf(-g2));
        float o  = 1.f / (1.f + __expf(-g3));

        float pC = a.prev_ok ? a.cPrev[(size_t)r * SS + j] : 0.f;
        float dC = a.delayed_ok ? a.cDel[(size_t)r * SS + j] : pC;
        float wC = a.delayed_ok ? (av * pC + (1.f - av) * dC) : pC;
        float nf = a.prev_ok ? (f * wC + (1.f - f) * n) : n;
        float wh2 = o * nf;

        a.cOut[(size_t)r * SS + j] = nf;

        if (j < OUTD) {
            float v = wh2;
            const size_t oidx = (size_t)r * OUTD + j;
            if (a.resid)  v += a.resid[oidx];
            if (a.f32out) a.f32out[oidx] = v;
            unsigned short hb = f2bf(v);
            a.outHi[oidx] = hb;
            a.outLo[oidx] = f2bf(v - bf2f(hb));
        } else {
            const int jo = j - OUTD;
            const size_t hidx = (size_t)r * HH + jo;
            unsigned short hb = f2bf(wh2);
            a.hHi[hidx] = hb;
            a.hLo[hidx] = f2bf(wh2 - bf2f(hb));
        }
    }
}

// ---------------------------------------------------------------------------
// W reorder: fp32 [4096][Kin] -> bf16 hi/lo fragment-linear:
// [strip64][plane2][step32][gate4][lane64][8]
// value = W[g*1024 + strip*16 + (l&15)][step*32 + (l>>4)*8 + q]
// ---------------------------------------------------------------------------
__global__ __launch_bounds__(256) void prep_reorderW(
    const float* __restrict__ W, int Kin, int nst32,
    unsigned short* __restrict__ Wr)
{
    const int strip = blockIdx.x;
    const int step  = blockIdx.y;
    const int g = threadIdx.x >> 6;
    const int l = threadIdx.x & 63;
    const int row = g * SS + strip * 16 + (l & 15);
    const int k   = step * 32 + (l >> 4) * 8;

    f32x4 v0 = *(const f32x4*)(W + (size_t)row * Kin + k);
    f32x4 v1 = *(const f32x4*)(W + (size_t)row * Kin + k + 4);
    short8 hi, lo;
    #pragma unroll
    for (int q = 0; q < 4; ++q) {
        unsigned short hb = f2bf(v0[q]);
        hi[q] = (short)hb; lo[q] = (short)f2bf(v0[q] - bf2f(hb));
        unsigned short hb2 = f2bf(v1[q]);
        hi[4+q] = (short)hb2; lo[4+q] = (short)f2bf(v1[q] - bf2f(hb2));
    }
    const size_t bHi = ((((size_t)strip * 2 + 0) * nst32 + step) * 4 + g) * 512 + (size_t)l * 8;
    const size_t bLo = ((((size_t)strip * 2 + 1) * nst32 + step) * 4 + g) * 512 + (size_t)l * 8;
    *(short8*)(Wr + bHi) = hi;
    *(short8*)(Wr + bLo) = lo;
}

// ---------------------------------------------------------------------------
// Adaptor: Y[1024][512] = A[1024][768] @ Wa[512][768]^T + ba, 3-pass MFMA.
// ---------------------------------------------------------------------------
__global__ __launch_bounds__(512) void adaptor_mfma(
    const unsigned short* __restrict__ Ahi, const unsigned short* __restrict__ Alo,
    const float* __restrict__ Wa, const float* __restrict__ ba,
    float* __restrict__ Y)
{
    const int tid  = threadIdx.x;
    const int lane = tid & 63;
    const int w    = tid >> 6;
    const int n0   = blockIdx.x * 16;
    const int r0   = blockIdx.y * 256 + w * 32;
    const int l15  = lane & 15;
    const int lk8  = (lane >> 4) * 8;

    f32x4 acc[2] = {{0,0,0,0},{0,0,0,0}};
    const float* Wrow = Wa + (size_t)(n0 + l15) * OUTD + lk8;
    for (int kb = 0; kb < OUTD; kb += 32) {
        f32x4 wv0 = *(const f32x4*)(Wrow + kb);
        f32x4 wv1 = *(const f32x4*)(Wrow + kb + 4);
        short8 whi, wlo;
        #pragma unroll
        for (int q = 0; q < 4; ++q) {
            unsigned short hb = f2bf(wv0[q]);
            whi[q] = (short)hb; wlo[q] = (short)f2bf(wv0[q] - bf2f(hb));
            unsigned short hb2 = f2bf(wv1[q]);
            whi[4+q] = (short)hb2; wlo[4+q] = (short)f2bf(wv1[q] - bf2f(hb2));
        }
        #pragma unroll
        for (int m = 0; m < 2; ++m) {
            const int r = r0 + m * 16 + l15;
            short8 ahi = *(const short8*)(Ahi + (size_t)r * OUTD + kb + lk8);
            short8 alo = *(const short8*)(Alo + (size_t)r * OUTD + kb + lk8);
            acc[m] = __builtin_amdgcn_mfma_f32_16x16x32_bf16(ahi, whi, acc[m], 0, 0, 0);
            acc[m] = __builtin_amdgcn_mfma_f32_16x16x32_bf16(alo, whi, acc[m], 0, 0, 0);
            acc[m] = __builtin_amdgcn_mfma_f32_16x16x32_bf16(ahi, wlo, acc[m], 0, 0, 0);
        }
    }
    const int c  = lane & 15;
    const int r4 = (lane >> 4) * 4;
    const float bb = ba[n0 + c];
    #pragma unroll
    for (int m = 0; m < 2; ++m)
        #pragma unroll
        for (int i = 0; i < 4; ++i)
            Y[(size_t)(r0 + m * 16 + r4 + i) * DOUT + n0 + c] = acc[m][i] + bb;
}

// ---------------------------------------------------------------------------
__global__ __launch_bounds__(256) void prep_split(
    const float* __restrict__ in, unsigned short* __restrict__ hi,
    unsigned short* __restrict__ lo, int n4)
{
    int i = blockIdx.x * 256 + threadIdx.x;
    if (i < n4) {
        f32x4 v = *(const f32x4*)(in + (size_t)i * 4);
        short4v sh, sl;
        #pragma unroll
        for (int j = 0; j < 4; ++j) {
            unsigned short hb = f2bf(v[j]);
            sh[j] = (short)hb; sl[j] = (short)f2bf(v[j] - bf2f(hb));
        }
        *(short4v*)(hi + (size_t)i * 4) = sh;
        *(short4v*)(lo + (size_t)i * 4) = sl;
    }
}

// ---------------------------------------------------------------------------
extern "C" void kernel_launch(void* const* d_in, const int* in_sizes, int n_in,
                              void* d_out, int out_size, void* d_ws, size_t ws_size,
                              hipStream_t stream)
{
    const float* x  = (const float*)d_in[0];
    const float* Wl[4] = {(const float*)d_in[1], (const float*)d_in[3],
                          (const float*)d_in[5], (const float*)d_in[7]};
    const float* bl[4] = {(const float*)d_in[2], (const float*)d_in[4],
                          (const float*)d_in[6], (const float*)d_in[8]};
    const float* Wa = (const float*)d_in[9];
    const float* ba = (const float*)d_in[10];
    float* out = (float*)d_out;

    // ---- workspace carve-up ----
    char* p = (char*)d_ws;
    auto take = [&](size_t bytes) { void* q = p; p += (bytes + 255) & ~(size_t)255; return q; };
    const size_t NX = (size_t)TT * BB * DIN;
    const size_t NH = (size_t)BB * HH;
    const size_t NC = (size_t)BB * SS;
    const size_t NO = (size_t)BB * OUTD;
    unsigned short* xHi = (unsigned short*)take(NX * 2);
    unsigned short* xLo = (unsigned short*)take(NX * 2);
    unsigned short* hHi = (unsigned short*)take(4 * TT * NH * 2);
    unsigned short* hLo = (unsigned short*)take(4 * TT * NH * 2);
    float*          cB  = (float*)take(4 * TT * NC * 4);
    unsigned short* oHi[4], *oLo[4];
    for (int l = 0; l < 4; ++l) {
        oHi[l] = (unsigned short*)take(TT * NO * 2);
        oLo[l] = (unsigned short*)take(TT * NO * 2);
    }
    float* o1F = (float*)take(TT * NO * 4);
    unsigned short* Wr[4];
    const int Kus[4] = {DIN, OUTD, OUTD, OUTD};
    const int dil[4] = {1, 2, 4, 8};
    int Kins[4], nst32s[4];
    for (int l = 0; l < 4; ++l) {
        Kins[l]   = Kus[l] + 2 * HH;
        nst32s[l] = Kins[l] / 32;
        Wr[l] = (unsigned short*)take((size_t)4 * SS * Kins[l] * 2 * 2);
    }

    // ---- prep ----
    hipLaunchKernelGGL(prep_split, dim3((NX / 4 + 255) / 256), dim3(256), 0, stream,
                       x, xHi, xLo, (int)(NX / 4));
    for (int l = 0; l < 4; ++l)
        hipLaunchKernelGGL(prep_reorderW, dim3(64, nst32s[l]), dim3(256), 0, stream,
                           Wl[l], Kins[l], nst32s[l], Wr[l]);

    // ---- wavefront: step s runs all cells (l, t=s-l) ----
    for (int s = 0; s <= TT - 1 + 3; ++s) {
        StepArgs sa;
        int n = 0;
        for (int l = 0; l < 4; ++l) {
            const int t = s - l;
            if (t < 0 || t >= TT) continue;
            CellDesc& d = sa.c[n++];
            const int Ku = Kus[l];
            const int prev_ok    = (t > 0);
            const int delayed_ok = (t >= dil[l]);
            const int tm1 = prev_ok ? t - 1 : 0;
            const int td  = delayed_ok ? t - dil[l] : tm1;
            const unsigned short* uHiL = (l == 0) ? xHi : oHi[l - 1];
            const unsigned short* uLoL = (l == 0) ? xLo : oLo[l - 1];
            unsigned short* hHl = hHi + (size_t)l * TT * NH;
            unsigned short* hLl = hLo + (size_t)l * TT * NH;
            float* cL = cB + (size_t)l * TT * NC;

            d.Wr   = Wr[l];
            d.bias = bl[l];
            d.uHi = uHiL + (size_t)t * BB * Ku;
            d.uLo = uLoL + (size_t)t * BB * Ku;
            d.hPrevHi = hHl + (size_t)tm1 * NH;
            d.hPrevLo = hLl + (size_t)tm1 * NH;
            d.hDelHi  = hHl + (size_t)td  * NH;
            d.hDelLo  = hLl + (size_t)td  * NH;
            d.cPrev = cL + (size_t)tm1 * NC;
            d.cDel  = cL + (size_t)td  * NC;
            d.cOut  = cL + (size_t)t   * NC;
            d.outHi = oHi[l] + (size_t)t * NO;
            d.outLo = oLo[l] + (size_t)t * NO;
            d.f32out = (l == 1) ? (o1F + (size_t)t * NO) : nullptr;
            d.resid  = (l == 3) ? (o1F + (size_t)t * NO) : nullptr;
            d.hHi = hHl + (size_t)t * NH;
            d.hLo = hLl + (size_t)t * NH;
            d.Ku = Ku; d.Kin = Kins[l];
            d.prev_ok = prev_ok; d.delayed_ok = delayed_ok;
            d.nst32 = nst32s[l]; d.pad = 0;
        }
        hipLaunchKernelGGL(cell_wave, dim3(n * 64), dim3(512), 0, stream, sa);
    }

    hipLaunchKernelGGL(adaptor_mfma, dim3(DOUT / 16, 4), dim3(512), 0, stream,
                       oHi[3], oLo[3], Wa, ba, out);
}